// Round 4
// baseline (316.608 us; speedup 1.0000x reference)
//
#include <hip/hip_runtime.h>

#define B_   64
#define E_   1024
#define N_   512
#define D_   64
#define HID_ 128
#define T_   5

typedef __bf16 bf16x8 __attribute__((ext_vector_type(8)));
typedef float f32x4 __attribute__((ext_vector_type(4)));

__device__ __forceinline__ unsigned short f2bu(float f) {
    union { float f; unsigned int u; } v; v.f = f;
    unsigned int r = (v.u + 0x7fffu + ((v.u >> 16) & 1u)) >> 16;  // RNE
    return (unsigned short)r;
}

#define MFMA16(a, b, c) __builtin_amdgcn_mfma_f32_16x16x32_bf16((a), (b), (c), 0, 0, 0)

// ---------------------------------------------------------------------------
// Prep: W1[t][d][h] -> W1T[t][h][d] bf16 ; W2[t][h][d] -> W2T[t][d][h] bf16
// ---------------------------------------------------------------------------
__global__ __launch_bounds__(256) void k_prep_w(const float* __restrict__ W1,
                                                const float* __restrict__ W2,
                                                unsigned short* __restrict__ W1T,
                                                unsigned short* __restrict__ W2T) {
    int idx = blockIdx.x * 256 + threadIdx.x;
    if (idx < T_ * HID_ * D_) {
        int t = idx / (HID_ * D_), rem = idx % (HID_ * D_);
        int h = rem / D_, d = rem % D_;
        W1T[idx] = f2bu(W1[(t * D_ + d) * HID_ + h]);
    } else {
        int j = idx - T_ * HID_ * D_;
        int t = j / (D_ * HID_), rem = j % (D_ * HID_);
        int d = rem / HID_, h = rem % HID_;
        W2T[j] = f2bu(W2[(t * HID_ + h) * D_ + d]);
    }
}

// ---------------------------------------------------------------------------
// Prep: ori[b][n][d] -> oriT[b][d][n] bf16, and out[b][n][64+d] = ori (fp32)
// grid (8, 64): x = n-tile of 64, y = b
// ---------------------------------------------------------------------------
__global__ __launch_bounds__(256) void k_ori_prep(const float* __restrict__ ori,
                                                  float* __restrict__ out,
                                                  unsigned short* __restrict__ oriT) {
    int b = blockIdx.y, n0 = blockIdx.x * 64;
    __shared__ float tl[64 * 65];
    int tid = threadIdx.x;
    int dl = tid & 63;
    #pragma unroll 4
    for (int p = 0; p < 16; ++p) {
        int nn = p * 4 + (tid >> 6);
        float v = ori[(size_t)(b * N_ + n0 + nn) * D_ + dl];
        out[(size_t)(b * N_ + n0 + nn) * 128 + 64 + dl] = v;
        tl[dl * 65 + nn] = v;
    }
    __syncthreads();
    #pragma unroll 4
    for (int p = 0; p < 16; ++p) {
        int dd = p * 4 + (tid >> 6);
        oriT[(size_t)(b * D_ + dd) * N_ + n0 + dl] = f2bu(tl[dd * 65 + dl]);
    }
}

// ---------------------------------------------------------------------------
// K1: edges[b][e][d] = sum_n H[b][e][n] * ori[b][n][d]   (bf16 out)
// grid (8, 64): x = e-tile of 128, y = b. 256 threads = 4 waves.
// ---------------------------------------------------------------------------
__global__ __launch_bounds__(256) void k_gemm_edges(const float* __restrict__ H,
                                                    const unsigned short* __restrict__ oriT,
                                                    unsigned short* __restrict__ edges) {
    int b = blockIdx.y, e0 = blockIdx.x * 128;
    __shared__ __align__(16) unsigned short aA[128 * 40];
    __shared__ __align__(16) unsigned short bB[64 * 40];
    int tid = threadIdx.x, w = tid >> 6, l = tid & 63, q = l >> 4, c = l & 15;
    const f32x4 zero = {0.f, 0.f, 0.f, 0.f};
    f32x4 acc[2][4];
    #pragma unroll
    for (int fm = 0; fm < 2; ++fm)
        #pragma unroll
        for (int fn = 0; fn < 4; ++fn) acc[fm][fn] = zero;

    for (int ks = 0; ks < 16; ++ks) {
        int k0 = ks * 32;
        #pragma unroll
        for (int p = 0; p < 4; ++p) {
            int u = p * 256 + tid, r = u >> 3, sg = u & 7;
            const float4 f = *(const float4*)&H[(size_t)(b * E_ + e0 + r) * N_ + k0 + sg * 4];
            ushort4 o;
            o.x = f2bu(f.x); o.y = f2bu(f.y); o.z = f2bu(f.z); o.w = f2bu(f.w);
            *(ushort4*)&aA[r * 40 + sg * 4] = o;
        }
        {
            int dd = tid >> 2, sg = tid & 3;
            *(uint4*)&bB[dd * 40 + sg * 8] =
                *(const uint4*)&oriT[(size_t)(b * D_ + dd) * N_ + k0 + sg * 8];
        }
        __syncthreads();
        bf16x8 a0 = *(const bf16x8*)&aA[(w * 32 + c) * 40 + q * 8];
        bf16x8 a1 = *(const bf16x8*)&aA[(w * 32 + 16 + c) * 40 + q * 8];
        #pragma unroll
        for (int fn = 0; fn < 4; ++fn) {
            bf16x8 bb = *(const bf16x8*)&bB[(fn * 16 + c) * 40 + q * 8];
            acc[0][fn] = MFMA16(a0, bb, acc[0][fn]);
            acc[1][fn] = MFMA16(a1, bb, acc[1][fn]);
        }
        __syncthreads();
    }
    #pragma unroll
    for (int fm = 0; fm < 2; ++fm)
        #pragma unroll
        for (int fn = 0; fn < 4; ++fn)
            #pragma unroll
            for (int i = 0; i < 4; ++i) {
                int e = e0 + w * 32 + fm * 16 + q * 4 + i;
                int d = fn * 16 + c;
                edges[(size_t)(b * E_ + e) * D_ + d] = f2bu(acc[fm][fn][i]);
            }
}

// ---------------------------------------------------------------------------
// K2: fused per-type MLP + mixture (MFMA).
//   h_t = relu(edges @ W1[t] + b1[t]) * w[b,e,t]
//   ef  = sum_t h_t @ W2[t] + sum_t w[b,e,t]*b2[t]
// Writes efT[b][d][e] (transposed, bf16) for K3.
// grid 1024: b = bx>>4, e0 = (bx&15)*64. 256 threads = 4 waves.
// ---------------------------------------------------------------------------
__global__ __launch_bounds__(256) void k_mlp(const unsigned short* __restrict__ edges,
                                             const float* __restrict__ ed,
                                             const float* __restrict__ b1,
                                             const float* __restrict__ b2,
                                             const unsigned short* __restrict__ W1T,
                                             const unsigned short* __restrict__ W2T,
                                             unsigned short* __restrict__ efT) {
    int bx = blockIdx.x;
    int b = bx >> 4, e0 = (bx & 15) * 64;
    __shared__ __align__(16) unsigned short a_sh[64 * 72];    // edges tile [r][d]
    __shared__ __align__(16) unsigned short w_sh[128 * 72];   // W1T [h][d] / W2T [d][hid]
    __shared__ __align__(16) unsigned short h_sh[64 * 136];   // h' tile [r][hid]
    __shared__ float wd_sh[320];                              // w[r][t]
    __shared__ float b1_sh[640];
    __shared__ float b2_sh[320];
    int tid = threadIdx.x, w = tid >> 6, l = tid & 63, q = l >> 4, c = l & 15;

    #pragma unroll
    for (int p = 0; p < 2; ++p) {
        int u = p * 256 + tid, r = u >> 3, sg = u & 7;
        *(uint4*)&a_sh[r * 72 + sg * 8] =
            *(const uint4*)&edges[(size_t)(b * E_ + e0 + r) * D_ + sg * 8];
    }
    // FIX: 320 > blockDim(256) — strided loop, not `if (tid < 320)`
    for (int u = tid; u < 320; u += 256) wd_sh[u] = ed[(size_t)(b * E_ + e0) * T_ + u];
    for (int u = tid; u < 640; u += 256) b1_sh[u] = b1[u];
    for (int u = tid; u < 320; u += 256) b2_sh[u] = b2[u];

    const f32x4 zero = {0.f, 0.f, 0.f, 0.f};
    f32x4 y[4];
    #pragma unroll
    for (int fn = 0; fn < 4; ++fn) y[fn] = zero;

    for (int t = 0; t < T_; ++t) {
        __syncthreads();  // B0: prev GEMM2 done with w_sh/h_sh; initial staging visible
        #pragma unroll
        for (int p = 0; p < 4; ++p) {  // W1T[t]: 128 rows x 64 bf16 = 1024 uint4
            int u = p * 256 + tid, hh = u >> 3, sg = u & 7;
            *(uint4*)&w_sh[hh * 72 + sg * 8] =
                *(const uint4*)&W1T[(t * HID_ + hh) * D_ + sg * 8];
        }
        __syncthreads();  // B1
        f32x4 hc[8];
        #pragma unroll
        for (int fn = 0; fn < 8; ++fn) hc[fn] = zero;
        #pragma unroll
        for (int ks = 0; ks < 2; ++ks) {
            bf16x8 a = *(const bf16x8*)&a_sh[(w * 16 + c) * 72 + ks * 32 + q * 8];
            #pragma unroll
            for (int fn = 0; fn < 8; ++fn) {
                bf16x8 bb = *(const bf16x8*)&w_sh[(fn * 16 + c) * 72 + ks * 32 + q * 8];
                hc[fn] = MFMA16(a, bb, hc[fn]);
            }
        }
        float wv[4];
        #pragma unroll
        for (int i = 0; i < 4; ++i) wv[i] = wd_sh[(w * 16 + q * 4 + i) * T_ + t];
        #pragma unroll
        for (int fn = 0; fn < 8; ++fn) {
            float b1v = b1_sh[t * HID_ + fn * 16 + c];
            #pragma unroll
            for (int i = 0; i < 4; ++i) {
                float v = hc[fn][i] + b1v;
                v = fmaxf(v, 0.0f) * wv[i];
                h_sh[(w * 16 + q * 4 + i) * 136 + fn * 16 + c] = f2bu(v);
            }
        }
        __syncthreads();  // B2: GEMM1 w_sh reads + h_sh writes complete
        #pragma unroll
        for (int p = 0; p < 4; ++p) {  // W2T[t]: 64 rows x 128 bf16 = 1024 uint4
            int u = p * 256 + tid, dd = u >> 4, sg = u & 15;
            *(uint4*)&w_sh[dd * 136 + sg * 8] =
                *(const uint4*)&W2T[(t * D_ + dd) * HID_ + sg * 8];
        }
        __syncthreads();  // B3
        #pragma unroll
        for (int ks = 0; ks < 4; ++ks) {
            bf16x8 a = *(const bf16x8*)&h_sh[(w * 16 + c) * 136 + ks * 32 + q * 8];
            #pragma unroll
            for (int fn = 0; fn < 4; ++fn) {
                bf16x8 bb = *(const bf16x8*)&w_sh[(fn * 16 + c) * 136 + ks * 32 + q * 8];
                y[fn] = MFMA16(a, bb, y[fn]);
            }
        }
    }
    // epilogue: + sum_t w*b2, write efT[b][d][e] transposed (bf16 ushort4 packs)
    #pragma unroll
    for (int fn = 0; fn < 4; ++fn) {
        int d = fn * 16 + c;
        ushort4 o;
        #pragma unroll
        for (int i = 0; i < 4; ++i) {
            int r = w * 16 + q * 4 + i;
            float s = y[fn][i];
            #pragma unroll
            for (int t = 0; t < T_; ++t) s += wd_sh[r * T_ + t] * b2_sh[t * D_ + d];
            ((unsigned short*)&o)[i] = f2bu(s);
        }
        *(ushort4*)&efT[(size_t)(b * D_ + d) * E_ + e0 + w * 16 + q * 4] = o;
    }
}

// ---------------------------------------------------------------------------
// K3: out[b][n][d] = sum_e H[b][e][n] * ef[b][e][d]   (first 64 cols of out)
// grid (4, 64): x = n-tile of 128, y = b. A-tile transposed via LDS.
// ---------------------------------------------------------------------------
__global__ __launch_bounds__(256) void k_gemm_out(const float* __restrict__ H,
                                                  const unsigned short* __restrict__ efT,
                                                  float* __restrict__ out) {
    int b = blockIdx.y, n0 = blockIdx.x * 128;
    __shared__ __align__(16) unsigned short aA[128 * 40];
    __shared__ __align__(16) unsigned short bB[64 * 40];
    int tid = threadIdx.x, w = tid >> 6, l = tid & 63, q = l >> 4, c = l & 15;
    const f32x4 zero = {0.f, 0.f, 0.f, 0.f};
    f32x4 acc[2][4];
    #pragma unroll
    for (int fm = 0; fm < 2; ++fm)
        #pragma unroll
        for (int fn = 0; fn < 4; ++fn) acc[fm][fn] = zero;

    for (int ks = 0; ks < 32; ++ks) {
        #pragma unroll
        for (int p = 0; p < 4; ++p) {
            int u = p * 256 + tid, ke = u >> 5, sg = u & 31;
            const float4 f = *(const float4*)&H[(size_t)(b * E_ + ks * 32 + ke) * N_ + n0 + sg * 4];
            aA[(sg * 4 + 0) * 40 + ke] = f2bu(f.x);
            aA[(sg * 4 + 1) * 40 + ke] = f2bu(f.y);
            aA[(sg * 4 + 2) * 40 + ke] = f2bu(f.z);
            aA[(sg * 4 + 3) * 40 + ke] = f2bu(f.w);
        }
        {
            int dd = tid >> 2, sg = tid & 3;
            *(uint4*)&bB[dd * 40 + sg * 8] =
                *(const uint4*)&efT[(size_t)(b * D_ + dd) * E_ + ks * 32 + sg * 8];
        }
        __syncthreads();
        bf16x8 a0 = *(const bf16x8*)&aA[(w * 32 + c) * 40 + q * 8];
        bf16x8 a1 = *(const bf16x8*)&aA[(w * 32 + 16 + c) * 40 + q * 8];
        #pragma unroll
        for (int fn = 0; fn < 4; ++fn) {
            bf16x8 bb = *(const bf16x8*)&bB[(fn * 16 + c) * 40 + q * 8];
            acc[0][fn] = MFMA16(a0, bb, acc[0][fn]);
            acc[1][fn] = MFMA16(a1, bb, acc[1][fn]);
        }
        __syncthreads();
    }
    #pragma unroll
    for (int fm = 0; fm < 2; ++fm)
        #pragma unroll
        for (int fn = 0; fn < 4; ++fn)
            #pragma unroll
            for (int i = 0; i < 4; ++i) {
                int n = n0 + w * 32 + fm * 16 + q * 4 + i;
                out[(size_t)(b * N_ + n) * 128 + fn * 16 + c] = acc[fm][fn][i];
            }
}

// ---------------------------------------------------------------------------
extern "C" void kernel_launch(void* const* d_in, const int* in_sizes, int n_in,
                              void* d_out, int out_size, void* d_ws, size_t ws_size,
                              hipStream_t stream) {
    const float* ed  = (const float*)d_in[0];  // [B,E,T]
    const float* H   = (const float*)d_in[1];  // [B,E,N]
    const float* ori = (const float*)d_in[2];  // [B,N,64]
    const float* W1  = (const float*)d_in[3];  // [T,64,128]
    const float* b1  = (const float*)d_in[4];  // [T,128]
    const float* W2  = (const float*)d_in[5];  // [T,128,64]
    const float* b2  = (const float*)d_in[6];  // [T,64]
    float* out = (float*)d_out;

    char* ws = (char*)d_ws;
    unsigned short* oriT  = (unsigned short*)ws; ws += (size_t)B_ * D_ * N_ * 2;   // 4 MB
    unsigned short* W1T   = (unsigned short*)ws; ws += (size_t)T_ * HID_ * D_ * 2;
    unsigned short* W2T   = (unsigned short*)ws; ws += (size_t)T_ * D_ * HID_ * 2;
    unsigned short* edges = (unsigned short*)ws; ws += (size_t)B_ * E_ * D_ * 2;   // 8 MB
    unsigned short* efT   = (unsigned short*)ws; ws += (size_t)B_ * D_ * E_ * 2;   // 8 MB

    hipLaunchKernelGGL(k_prep_w, dim3(320), dim3(256), 0, stream, W1, W2, W1T, W2T);
    hipLaunchKernelGGL(k_ori_prep, dim3(8, 64), dim3(256), 0, stream, ori, out, oriT);
    hipLaunchKernelGGL(k_gemm_edges, dim3(8, 64), dim3(256), 0, stream, H, oriT, edges);
    hipLaunchKernelGGL(k_mlp, dim3(1024), dim3(256), 0, stream, edges, ed, b1, b2, W1T, W2T, efT);
    hipLaunchKernelGGL(k_gemm_out, dim3(4, 64), dim3(256), 0, stream, H, efT, out);
}